// Round 10
// baseline (2693.120 us; speedup 1.0000x reference)
//
#include <hip/hip_runtime.h>

// DSDMSR_x8: 13-unit SRCNN cascade, fp32 I/O, bf16 MFMA compute.
// Per 12x12 output tile (256 thr / 4 waves, __launch_bounds__(256,3), 3 blk/CU):
// Disjoint accumulator lifetimes (spill-free structure from r8) with register
// peaks genuinely under the 3-wave/SIMD cap (~168 unified regs):
//   phase 1: conv1 9x9 1->64, two ci-halves (acc 56 AGPR), ALL h1 -> LDS;
//            sIn stored bf16 (identical math; A-build reads ushorts directly)
//   phase 2: conv2 5x5 64->32 (acc2[4][2]=32 AGPR), n-SPLIT B staging:
//            Ba[5]/Bb[5] register double-buffer (40 VGPR), 10 groups x 2 n-passes
//   phase 3: conv3 5x5 32->1 per-tap MFMA (K=32)
// LDS 52928 B (-> 53248 alloc, x3 = 159.7 KB <= 160 KB):
//   sH1 8 planes x 3208 sh | sIn bf16 784 (union sW3 800) | h2 unioned into sH1.
// Spill canary: WRITE_SIZE must stay ~5 MB (r8-verified). r7/r9 spills showed
// as GB-scale FETCH/WRITE.

typedef unsigned short ushort_t;
typedef __attribute__((ext_vector_type(8))) short short8;   // 8 bf16
typedef __attribute__((ext_vector_type(4))) float f32x4;

__device__ __forceinline__ float us2f(ushort_t u) { return __uint_as_float(((unsigned int)u) << 16); }
__device__ __forceinline__ ushort_t f2us(float f) {
    unsigned int x = __float_as_uint(f);
    return (ushort_t)((x + 0x7fffu + ((x >> 16) & 1u)) >> 16);
}

#define MFMA16(a, b, c) __builtin_amdgcn_mfma_f32_16x16x32_bf16((a), (b), (c), 0, 0, 0)

// ---------------------------------------------------------------------------
// Weight prep (bf16, MFMA-fragment-friendly layouts):
//  w1t [u][kc3][cig4][ch64][8]          (k = kc*32+cig*8+e, zero for k>=81)
//  w2t [u][c2][dx5][dy5][cig4][co32][8] (ci = c*32+cig*8+e, tap = dy*5+dx)
//  w3t [u][tap25][ci32]
// ---------------------------------------------------------------------------
__global__ __launch_bounds__(256) void prep_weights(
    const float* __restrict__ W1, const float* __restrict__ W2, const float* __restrict__ W3,
    ushort_t* __restrict__ w1t, ushort_t* __restrict__ w2t, ushort_t* __restrict__ w3t)
{
    int i = blockIdx.x * 256 + threadIdx.x;
    if (i < 13 * 3 * 4 * 64 * 8) {           // 79872
        int e = i & 7, ch = (i >> 3) & 63, cig = (i >> 9) & 3;
        int r = i >> 11;                     // u*3 + kc
        int kc = r % 3, u = r / 3;
        int k = kc * 32 + cig * 8 + e;
        w1t[i] = (k < 81) ? f2us(W1[(u * 64 + ch) * 81 + k]) : (ushort_t)0;
    }
    if (i < 665600) {                        // 13*2*25*4*32*8
        int e = i & 7, co = (i >> 3) & 31, cig = (i >> 8) & 3;
        int r = i >> 10;                     // (u*2+c)*25 + s, s = dx*5+dy
        int s = r % 25, cc = r / 25;
        int dx = s / 5, dy = s - 5 * dx;
        int c = cc & 1, u = cc >> 1;
        int tap = dy * 5 + dx;
        int ci = c * 32 + cig * 8 + e;
        w2t[i] = f2us(W2[((u * 32 + co) * 64 + ci) * 25 + tap]);
    }
    if (i < 13 * 25 * 32) {                  // 10400
        int ci = i & 31, r = i >> 5;
        int tap = r % 25, u = r / 25;
        w3t[i] = f2us(W3[(u * 32 + ci) * 25 + tap]);
    }
}

// ---------------------------------------------------------------------------
__global__ __launch_bounds__(256, 3) void srcnn_mfma(
    const float* __restrict__ in, int H, int W,
    const ushort_t* __restrict__ w1t, const ushort_t* __restrict__ w2t,
    const ushort_t* __restrict__ w3t,
    const float* __restrict__ gB1, const float* __restrict__ gB2,
    const float* __restrict__ gB3,
    int unitBase, float* __restrict__ out, int s2)
{
    __shared__ __align__(16) char smem[52928];
    ushort_t* sH1  = (ushort_t*)smem;             // 8 planes x 3208 shorts = 51328 B
    ushort_t* sInU = (ushort_t*)(smem + 51328);   // 784 bf16 (conv1 only)
    ushort_t* sW3  = (ushort_t*)(smem + 51328);   // 800 u16 (after conv1)
    ushort_t* sH2  = (ushort_t*)smem;             // h2 4 x 2064 shorts (after conv2)

    const int t = threadIdx.x, lane = t & 63, wv = t >> 6;
    const int q = lane >> 4, l15 = lane & 15;
    const int z = blockIdx.z;
    const int k4 = (s2 == 2) ? (z >> 2) : 0;
    const int b  = (s2 == 2) ? (z & 3)  : z;
    const int unit = unitBase + k4;
    const int ppx = k4 & 1, ppy = k4 >> 1;
    const int ox0 = blockIdx.x * 12, oy0 = blockIdx.y * 12;
    const int outW = W * s2;
    const int outH = H * s2;
    const float* inb = in + (size_t)b * H * W;

    const char* w2u = (const char*)w2t + (size_t)unit * 102400;

    // conv2 B: per-n 5-frag register double buffer (Ba/Bb), loaded from L2.
    // group p (c=p/5, dx=p%5), n-tile n (co n*16..n*16+15): frag dy at
    //   p*10240 + dy*2048 + q*512 + (n*16+l15)*16
    short8 Ba[5], Bb[5];
    auto loadB5 = [&](short8* buf, int p, int n) {
        const char* g = w2u + (size_t)p * 10240 + q * 512 + (n * 16 + l15) * 16;
#pragma unroll
        for (int dy = 0; dy < 5; ++dy)
            buf[dy] = *(const short8*)(g + dy * 2048);
    };
    loadB5(Ba, 0, 0);   // in flight through input staging + conv1

    // stage input 28x28 (origin -8, zero-padded) as bf16
    for (int idx = t; idx < 784; idx += 256) {
        int y = idx / 28, x = idx - 28 * y;
        int gy = oy0 - 8 + y, gx = ox0 - 8 + x;
        sInU[idx] = (gy >= 0 && gy < H && gx >= 0 && gx < W)
                    ? f2us(inb[(size_t)gy * W + gx]) : (ushort_t)0;
    }
    __syncthreads();

    const ushort_t* w1u = w1t + (size_t)unit * (3 * 4 * 64 * 8);

    // ---- phase 1: conv1, two ci-halves; only acc1h (56 AGPR) live ----
    for (int c = 0; c < 2; ++c) {
        f32x4 acc1h[7][2];
#pragma unroll
        for (int i = 0; i < 7; ++i) { acc1h[i][0] = (f32x4){0.f,0.f,0.f,0.f}; acc1h[i][1] = (f32x4){0.f,0.f,0.f,0.f}; }

        for (int kc = 0; kc < 3; ++kc) {
            short8 bh0 = *(const short8*)&w1u[((kc * 4 + q) * 64 + (c * 32 + l15)) * 8];
            short8 bh1 = *(const short8*)&w1u[((kc * 4 + q) * 64 + (c * 32 + 16 + l15)) * 8];
            int toff8[8];
#pragma unroll
            for (int j = 0; j < 8; ++j) {
                int k = kc * 32 + q * 8 + j;
                if (k < 81) { int ty = (k * 57) >> 9; toff8[j] = ty * 28 + (k - 9 * ty); }
                else toff8[j] = -1;
            }
#pragma unroll
            for (int im = 0; im < 7; ++im) {
                int m = wv + im * 4;
                if (m < 25) {
                    int px = m * 16 + l15;            // 0..399 (20x20 h1 grid)
                    int py1 = (px * 205) >> 12;
                    int base = py1 * 28 + (px - 20 * py1);
                    union { short8 v; ushort_t u[8]; } a;
#pragma unroll
                    for (int j = 0; j < 8; ++j) {
                        int o = toff8[j];
                        a.u[j] = (o >= 0) ? sInU[base + o] : (ushort_t)0;
                    }
                    acc1h[im][0] = MFMA16(a.v, bh0, acc1h[im][0]);
                    acc1h[im][1] = MFMA16(a.v, bh1, acc1h[im][1]);
                }
            }
        }

        // writeback this half: sH1 [cig8][px400][8], plane stride 3208 (skew)
        float bias0 = gB1[unit * 64 + c * 32 + l15];
        float bias1 = gB1[unit * 64 + c * 32 + 16 + l15];
#pragma unroll
        for (int im = 0; im < 7; ++im) {
            int m = wv + im * 4;
            if (m < 25) {
#pragma unroll
                for (int nn = 0; nn < 2; ++nn) {
                    float bias = nn ? bias1 : bias0;
                    int cig = c * 4 + ((nn * 16 + l15) >> 3);
                    int e   = l15 & 7;
#pragma unroll
                    for (int r = 0; r < 4; ++r) {
                        int px = m * 16 + q * 4 + r;
                        int py1 = (px * 205) >> 12;
                        int px1 = px - 20 * py1;
                        int gy = oy0 - 4 + py1, gx = ox0 - 4 + px1;
                        float v = fmaxf(acc1h[im][nn][r] + bias, 0.f);
                        if (!(gy >= 0 && gy < H && gx >= 0 && gx < W)) v = 0.f;
                        sH1[cig * 3208 + px * 8 + e] = f2us(v);
                    }
                }
            }
        }
    }
    __syncthreads();   // all h1 written; all sInU reads done

    // stage w3 into sInU region (dead); visible to conv3 via the post-h2 barrier
    {
        const ushort_t* w3u = w3t + unit * 800;
        for (int i = t; i < 800; i += 256) sW3[i] = w3u[i];
    }

    // ---- phase 2: conv2; acc2 (32 AGPR) + Ba/Bb (40 VGPR) live ----
    f32x4 acc2[4][2];
#pragma unroll
    for (int i = 0; i < 4; ++i) { acc2[i][0] = (f32x4){0.f,0.f,0.f,0.f}; acc2[i][1] = (f32x4){0.f,0.f,0.f,0.f}; }

#pragma unroll
    for (int n = 0; n < 2; ++n) {
#pragma unroll
        for (int p = 0; p < 10; ++p) {
            const int idx = n * 10 + p;
            const short8* cur = (idx & 1) ? Bb : Ba;
            short8* nxt = (idx & 1) ? Ba : Bb;
            if (p < 9)           loadB5(nxt, p + 1, n);
            else if (n == 0)     loadB5(nxt, 0, 1);

            const int c = p / 5, dx = p - 5 * (p / 5);
            const ushort_t* base = &sH1[(c * 4 + q) * 3208];
#pragma unroll
            for (int rel = 0; rel < 8; ++rel) {
                int row = wv * 4 + rel;
                short8 a = *(const short8*)&base[(row * 20 + l15 + dx) * 8];
                const int dylo = rel - 3 < 0 ? 0 : rel - 3;
                const int dyhi = rel < 4 ? rel : 4;
#pragma unroll
                for (int dy = 0; dy < 5; ++dy) {
                    if (dy >= dylo && dy <= dyhi) {
                        int im = rel - dy;
                        acc2[im][n] = MFMA16(a, cur[dy], acc2[im][n]);
                    }
                }
            }
        }
    }
    __syncthreads();   // all sH1 reads done before h2 overwrites it

    // ---- h2 writeback [cog4][px256][8], stride 2064, into sH1 region ----
    {
        float bias0 = gB2[unit * 32 + l15];
        float bias1 = gB2[unit * 32 + 16 + l15];
#pragma unroll
        for (int im = 0; im < 4; ++im) {
            int hy = wv * 4 + im;
#pragma unroll
            for (int n = 0; n < 2; ++n) {
                int co = n * 16 + l15;
                float bias = n ? bias1 : bias0;
                int cog = co >> 3, e = co & 7;
#pragma unroll
                for (int r = 0; r < 4; ++r) {
                    int hx = q * 4 + r;
                    int gy = oy0 - 2 + hy, gx = ox0 - 2 + hx;
                    float v = fmaxf(acc2[im][n][r] + bias, 0.f);
                    if (!(gy >= 0 && gy < H && gx >= 0 && gx < W)) v = 0.f;
                    sH2[cog * 2064 + (hy * 16 + hx) * 8 + e] = f2us(v);
                }
            }
        }
    }
    __syncthreads();

    // ---- phase 3: conv3 per-tap MFMA, K=32, 9 m-tiles over 144 out px ----
    float b3 = gB3[unit];
    int nm = (wv == 0) ? 3 : 2;
    for (int jm = 0; jm < nm; ++jm) {
        int mt = wv + 4 * jm;                        // 0..8
        int p = mt * 16 + l15;                       // 0..143
        int oy2 = (p * 683) >> 13, ox2 = p - 12 * oy2;
        f32x4 acc = (f32x4){0.f, 0.f, 0.f, 0.f};
        for (int tap = 0; tap < 25; ++tap) {
            int dy = (tap * 13) >> 6, dx = tap - 5 * dy;
            int h2px = (oy2 + dy) * 16 + ox2 + dx;
            short8 a = *(const short8*)&sH2[q * 2064 + h2px * 8];
            short8 w = *(const short8*)&sW3[tap * 32 + q * 8];
            acc = MFMA16(a, w, acc);
        }
        if (l15 == 0) {
#pragma unroll
            for (int r = 0; r < 4; ++r) {
                int pp = mt * 16 + q * 4 + r;
                int oy = (pp * 683) >> 13, ox = pp - 12 * oy;
                int gy = oy0 + oy, gx = ox0 + ox;
                if (gy < H && gx < W) {
                    size_t o = (size_t)b * outW * outH + (size_t)(gy * s2 + ppy) * outW + (gx * s2 + ppx);
                    out[o] = acc[r] + b3;
                }
            }
        }
    }
}

// ---------------------------------------------------------------------------
// MSF input: up4(out_x2) + up2(out_x4) + out_x8 (bilinear, half-pixel, clamped)
// ---------------------------------------------------------------------------
__device__ __forceinline__ void ax_w(int i, float inv_s, int n, int& i0, int& i1, float& w1) {
    float c  = (i + 0.5f) * inv_s - 0.5f;
    float fl = floorf(c);
    w1 = c - fl;
    int ii = (int)fl;
    i0 = ii < 0 ? 0 : ii;
    i1 = (ii + 1 >= n) ? (n - 1) : (ii + 1);
}

__global__ __launch_bounds__(256) void msf_in_kernel(
    const float* __restrict__ f2, const float* __restrict__ f4,
    const float* __restrict__ f8, float* __restrict__ dst)
{
    int idx = blockIdx.x * 256 + threadIdx.x;   // 4*512*512
    int x = idx & 511;
    int y = (idx >> 9) & 511;
    int b = idx >> 18;

    int y0, y1, x0, x1;
    float wy, wx;

    ax_w(y, 0.25f, 128, y0, y1, wy);
    ax_w(x, 0.25f, 128, x0, x1, wx);
    const float* p2 = f2 + (size_t)b * 16384;
    float v4 = (1.f - wy) * ((1.f - wx) * p2[y0 * 128 + x0] + wx * p2[y0 * 128 + x1])
             +        wy  * ((1.f - wx) * p2[y1 * 128 + x0] + wx * p2[y1 * 128 + x1]);

    ax_w(y, 0.5f, 256, y0, y1, wy);
    ax_w(x, 0.5f, 256, x0, x1, wx);
    const float* p4 = f4 + (size_t)b * 65536;
    float v2 = (1.f - wy) * ((1.f - wx) * p4[y0 * 256 + x0] + wx * p4[y0 * 256 + x1])
             +        wy  * ((1.f - wx) * p4[y1 * 256 + x0] + wx * p4[y1 * 256 + x1]);

    dst[idx] = v4 + v2 + f8[idx];
}

// ---------------------------------------------------------------------------
extern "C" void kernel_launch(void* const* d_in, const int* in_sizes, int n_in,
                              void* d_out, int out_size, void* d_ws, size_t ws_size,
                              hipStream_t stream)
{
    (void)in_sizes; (void)n_in; (void)out_size; (void)ws_size;

    const float* image = (const float*)d_in[0];
    const float* W1    = (const float*)d_in[1];
    const float* B1    = (const float*)d_in[2];
    const float* W2    = (const float*)d_in[3];
    const float* B2    = (const float*)d_in[4];
    const float* W3    = (const float*)d_in[5];
    const float* B3    = (const float*)d_in[6];

    float* out = (float*)d_out;
    float* o2 = out;                 // (4,1,128,128)
    float* o4 = out + 65536;         // (4,1,256,256)
    float* o8 = out + 327680;        // (4,1,512,512)
    float* om = out + 1376256;       // msf (4,1,512,512)

    float*    fm  = (float*)d_ws;                              // 4 MB
    ushort_t* w1t = (ushort_t*)((char*)d_ws + 4194304);        // 79872 u16
    ushort_t* w2t = (ushort_t*)((char*)d_ws + 4354048);        // 665600 u16
    ushort_t* w3t = (ushort_t*)((char*)d_ws + 5685248);        // 10400 u16

    prep_weights<<<2600, 256, 0, stream>>>(W1, W2, W3, w1t, w2t, w3t);

    srcnn_mfma<<<dim3(6, 6, 16), 256, 0, stream>>>(
        image, 64, 64, w1t, w2t, w3t, B1, B2, B3, 0, o2, 2);
    srcnn_mfma<<<dim3(11, 11, 16), 256, 0, stream>>>(
        o2, 128, 128, w1t, w2t, w3t, B1, B2, B3, 4, o4, 2);
    srcnn_mfma<<<dim3(22, 22, 16), 256, 0, stream>>>(
        o4, 256, 256, w1t, w2t, w3t, B1, B2, B3, 8, o8, 2);
    msf_in_kernel<<<4096, 256, 0, stream>>>(o2, o4, o8, fm);
    srcnn_mfma<<<dim3(43, 43, 4), 256, 0, stream>>>(
        fm, 512, 512, w1t, w2t, w3t, B1, B2, B3, 12, om, 1);
}

// Round 11
// 1243.957 us; speedup vs baseline: 2.1650x; 2.1650x over previous
//
#include <hip/hip_runtime.h>

// DSDMSR_x8: 13-unit SRCNN cascade, fp32 I/O, bf16 MFMA compute.
// Per 12x12 output tile (256 thr / 4 waves, __launch_bounds__(256,2) -- NEVER
// force occupancy: r6/r7/r9/r10 all spilled when capped. Instead cut true
// register demand (<~170 unified) so HW naturally runs 3 waves/SIMD; LDS
// 52928 B (53248 alloc) x3 = 159.7 KB <= 160 KB.
//   phase 1: conv1 9x9 1->64, two ci-halves (acc 56 AGPR), kc unroll 1,
//            im unroll 2; sIn bf16; ALL h1 -> LDS
//   phase 2: conv2 5x5 64->32 (acc2 32 AGPR), n-split B: per-(n,c) prologue +
//            dx-parity ping-pong (40 VGPR), unroll 1 on n/c to stop hoisting
//   phase 3: conv3 5x5 32->1, tap-outer, w-frag hoisted (acc3 12 AGPR)
// Spill canary: WRITE_SIZE must stay ~5 MB (r8-verified baseline).

typedef unsigned short ushort_t;
typedef __attribute__((ext_vector_type(8))) short short8;   // 8 bf16
typedef __attribute__((ext_vector_type(4))) float f32x4;

__device__ __forceinline__ float us2f(ushort_t u) { return __uint_as_float(((unsigned int)u) << 16); }
__device__ __forceinline__ ushort_t f2us(float f) {
    unsigned int x = __float_as_uint(f);
    return (ushort_t)((x + 0x7fffu + ((x >> 16) & 1u)) >> 16);
}

#define MFMA16(a, b, c) __builtin_amdgcn_mfma_f32_16x16x32_bf16((a), (b), (c), 0, 0, 0)

// ---------------------------------------------------------------------------
// Weight prep (bf16, MFMA-fragment-friendly layouts):
//  w1t [u][kc3][cig4][ch64][8]          (k = kc*32+cig*8+e, zero for k>=81)
//  w2t [u][c2][dx5][dy5][cig4][co32][8] (ci = c*32+cig*8+e, tap = dy*5+dx)
//  w3t [u][tap25][ci32]
// ---------------------------------------------------------------------------
__global__ __launch_bounds__(256) void prep_weights(
    const float* __restrict__ W1, const float* __restrict__ W2, const float* __restrict__ W3,
    ushort_t* __restrict__ w1t, ushort_t* __restrict__ w2t, ushort_t* __restrict__ w3t)
{
    int i = blockIdx.x * 256 + threadIdx.x;
    if (i < 13 * 3 * 4 * 64 * 8) {           // 79872
        int e = i & 7, ch = (i >> 3) & 63, cig = (i >> 9) & 3;
        int r = i >> 11;                     // u*3 + kc
        int kc = r % 3, u = r / 3;
        int k = kc * 32 + cig * 8 + e;
        w1t[i] = (k < 81) ? f2us(W1[(u * 64 + ch) * 81 + k]) : (ushort_t)0;
    }
    if (i < 665600) {                        // 13*2*25*4*32*8
        int e = i & 7, co = (i >> 3) & 31, cig = (i >> 8) & 3;
        int r = i >> 10;                     // (u*2+c)*25 + s, s = dx*5+dy
        int s = r % 25, cc = r / 25;
        int dx = s / 5, dy = s - 5 * dx;
        int c = cc & 1, u = cc >> 1;
        int tap = dy * 5 + dx;
        int ci = c * 32 + cig * 8 + e;
        w2t[i] = f2us(W2[((u * 32 + co) * 64 + ci) * 25 + tap]);
    }
    if (i < 13 * 25 * 32) {                  // 10400
        int ci = i & 31, r = i >> 5;
        int tap = r % 25, u = r / 25;
        w3t[i] = f2us(W3[(u * 32 + ci) * 25 + tap]);
    }
}

// ---------------------------------------------------------------------------
__global__ __launch_bounds__(256, 2) void srcnn_mfma(
    const float* __restrict__ in, int H, int W,
    const ushort_t* __restrict__ w1t, const ushort_t* __restrict__ w2t,
    const ushort_t* __restrict__ w3t,
    const float* __restrict__ gB1, const float* __restrict__ gB2,
    const float* __restrict__ gB3,
    int unitBase, float* __restrict__ out, int s2)
{
    __shared__ __align__(16) char smem[52928];
    ushort_t* sH1  = (ushort_t*)smem;             // 8 planes x 3208 shorts = 51328 B
    ushort_t* sInU = (ushort_t*)(smem + 51328);   // 784 bf16 (conv1 only)
    ushort_t* sW3  = (ushort_t*)(smem + 51328);   // 800 u16 (after conv1)
    ushort_t* sH2  = (ushort_t*)smem;             // h2 4 x 2064 shorts (after conv2)

    const int t = threadIdx.x, lane = t & 63, wv = t >> 6;
    const int q = lane >> 4, l15 = lane & 15;
    const int z = blockIdx.z;
    const int k4 = (s2 == 2) ? (z >> 2) : 0;
    const int b  = (s2 == 2) ? (z & 3)  : z;
    const int unit = unitBase + k4;
    const int ppx = k4 & 1, ppy = k4 >> 1;
    const int ox0 = blockIdx.x * 12, oy0 = blockIdx.y * 12;
    const int outW = W * s2;
    const int outH = H * s2;
    const float* inb = in + (size_t)b * H * W;

    const char* w2u = (const char*)w2t + (size_t)unit * 102400;

    // conv2 B: 5-frag buffer loaded from L2 for group p (c=p/5 baked into p),
    // n-tile n: frag dy at p*10240 + dy*2048 + q*512 + (n*16+l15)*16
    auto loadB5 = [&](short8* buf, int p, int n) {
        const char* g = w2u + (size_t)p * 10240 + q * 512 + (n * 16 + l15) * 16;
#pragma unroll
        for (int dy = 0; dy < 5; ++dy)
            buf[dy] = *(const short8*)(g + dy * 2048);
    };

    // stage input 28x28 (origin -8, zero-padded) as bf16
    for (int idx = t; idx < 784; idx += 256) {
        int y = idx / 28, x = idx - 28 * y;
        int gy = oy0 - 8 + y, gx = ox0 - 8 + x;
        sInU[idx] = (gy >= 0 && gy < H && gx >= 0 && gx < W)
                    ? f2us(inb[(size_t)gy * W + gx]) : (ushort_t)0;
    }
    __syncthreads();

    const ushort_t* w1u = w1t + (size_t)unit * (3 * 4 * 64 * 8);

    // ---- phase 1: conv1, two ci-halves; only acc1h (56 AGPR) live ----
#pragma unroll 1
    for (int c = 0; c < 2; ++c) {
        f32x4 acc1h[7][2];
#pragma unroll
        for (int i = 0; i < 7; ++i) { acc1h[i][0] = (f32x4){0.f,0.f,0.f,0.f}; acc1h[i][1] = (f32x4){0.f,0.f,0.f,0.f}; }

#pragma unroll 1
        for (int kc = 0; kc < 3; ++kc) {
            short8 bh0 = *(const short8*)&w1u[((kc * 4 + q) * 64 + (c * 32 + l15)) * 8];
            short8 bh1 = *(const short8*)&w1u[((kc * 4 + q) * 64 + (c * 32 + 16 + l15)) * 8];
            int toff8[8];
#pragma unroll
            for (int j = 0; j < 8; ++j) {
                int k = kc * 32 + q * 8 + j;
                if (k < 81) { int ty = (k * 57) >> 9; toff8[j] = ty * 28 + (k - 9 * ty); }
                else toff8[j] = -1;
            }
#pragma unroll 2
            for (int im = 0; im < 7; ++im) {
                int m = wv + im * 4;
                if (m < 25) {
                    int px = m * 16 + l15;            // 0..399 (20x20 h1 grid)
                    int py1 = (px * 205) >> 12;
                    int base = py1 * 28 + (px - 20 * py1);
                    union { short8 v; ushort_t u[8]; } a;
#pragma unroll
                    for (int j = 0; j < 8; ++j) {
                        int o = toff8[j];
                        a.u[j] = (o >= 0) ? sInU[base + o] : (ushort_t)0;
                    }
                    acc1h[im][0] = MFMA16(a.v, bh0, acc1h[im][0]);
                    acc1h[im][1] = MFMA16(a.v, bh1, acc1h[im][1]);
                }
            }
        }

        // writeback this half: sH1 [cig8][px400][8], plane stride 3208 (skew)
        float bias0 = gB1[unit * 64 + c * 32 + l15];
        float bias1 = gB1[unit * 64 + c * 32 + 16 + l15];
#pragma unroll
        for (int im = 0; im < 7; ++im) {
            int m = wv + im * 4;
            if (m < 25) {
#pragma unroll
                for (int nn = 0; nn < 2; ++nn) {
                    float bias = nn ? bias1 : bias0;
                    int cig = c * 4 + ((nn * 16 + l15) >> 3);
                    int e   = l15 & 7;
#pragma unroll
                    for (int r = 0; r < 4; ++r) {
                        int px = m * 16 + q * 4 + r;
                        int py1 = (px * 205) >> 12;
                        int px1 = px - 20 * py1;
                        int gy = oy0 - 4 + py1, gx = ox0 - 4 + px1;
                        float v = fmaxf(acc1h[im][nn][r] + bias, 0.f);
                        if (!(gy >= 0 && gy < H && gx >= 0 && gx < W)) v = 0.f;
                        sH1[cig * 3208 + px * 8 + e] = f2us(v);
                    }
                }
            }
        }
    }
    __syncthreads();   // all h1 written; all sInU reads done

    // stage w3 into sInU region (dead); visible to conv3 via the post-h2 barrier
    {
        const ushort_t* w3u = w3t + unit * 800;
        for (int i = t; i < 800; i += 256) sW3[i] = w3u[i];
    }

    // ---- phase 2: conv2; acc2 (32 AGPR) + ping-pong B (40 VGPR) live ----
    f32x4 acc2[4][2];
#pragma unroll
    for (int i = 0; i < 4; ++i) { acc2[i][0] = (f32x4){0.f,0.f,0.f,0.f}; acc2[i][1] = (f32x4){0.f,0.f,0.f,0.f}; }

#pragma unroll 1
    for (int n = 0; n < 2; ++n) {
#pragma unroll 1
        for (int c = 0; c < 2; ++c) {
            short8 Ba[5], Bb[5];
            loadB5(Ba, c * 5, n);
            const ushort_t* base = &sH1[(c * 4 + q) * 3208];
#pragma unroll
            for (int dx = 0; dx < 5; ++dx) {
                const short8* cur = (dx & 1) ? Bb : Ba;   // compile-time (dx unrolled)
                short8*       nxt = (dx & 1) ? Ba : Bb;
                if (dx < 4) loadB5(nxt, c * 5 + dx + 1, n);
#pragma unroll
                for (int rel = 0; rel < 8; ++rel) {
                    int row = wv * 4 + rel;
                    short8 a = *(const short8*)&base[(row * 20 + l15 + dx) * 8];
                    const int dylo = rel - 3 < 0 ? 0 : rel - 3;
                    const int dyhi = rel < 4 ? rel : 4;
#pragma unroll
                    for (int dy = 0; dy < 5; ++dy) {
                        if (dy >= dylo && dy <= dyhi) {
                            int im = rel - dy;
                            acc2[im][n] = MFMA16(a, cur[dy], acc2[im][n]);
                        }
                    }
                }
            }
        }
    }
    __syncthreads();   // all sH1 reads done before h2 overwrites it

    // ---- h2 writeback [cog4][px256][8], stride 2064, into sH1 region ----
    {
        float bias0 = gB2[unit * 32 + l15];
        float bias1 = gB2[unit * 32 + 16 + l15];
#pragma unroll
        for (int im = 0; im < 4; ++im) {
            int hy = wv * 4 + im;
#pragma unroll
            for (int n = 0; n < 2; ++n) {
                int co = n * 16 + l15;
                float bias = n ? bias1 : bias0;
                int cog = co >> 3, e = co & 7;
#pragma unroll
                for (int r = 0; r < 4; ++r) {
                    int hx = q * 4 + r;
                    int gy = oy0 - 2 + hy, gx = ox0 - 2 + hx;
                    float v = fmaxf(acc2[im][n][r] + bias, 0.f);
                    if (!(gy >= 0 && gy < H && gx >= 0 && gx < W)) v = 0.f;
                    sH2[cog * 2064 + (hy * 16 + hx) * 8 + e] = f2us(v);
                }
            }
        }
    }
    __syncthreads();

    // ---- phase 3: conv3, tap-outer, w-frag hoisted; acc3 12 AGPR ----
    float b3 = gB3[unit];
    const int nm = (wv == 0) ? 3 : 2;
    int oyj[3], oxj[3];
#pragma unroll
    for (int jm = 0; jm < 3; ++jm) {
        int p = (wv + 4 * jm) * 16 + l15;            // 0..143 valid range
        oyj[jm] = (p * 683) >> 13;
        oxj[jm] = p - 12 * oyj[jm];
    }
    f32x4 acc3[3];
#pragma unroll
    for (int jm = 0; jm < 3; ++jm) acc3[jm] = (f32x4){0.f, 0.f, 0.f, 0.f};

#pragma unroll 1
    for (int tap = 0; tap < 25; ++tap) {
        int dy = (tap * 13) >> 6, dx = tap - 5 * dy;
        short8 w = *(const short8*)&sW3[tap * 32 + q * 8];
#pragma unroll
        for (int jm = 0; jm < 3; ++jm) {
            if (jm < nm) {
                int h2px = (oyj[jm] + dy) * 16 + oxj[jm] + dx;
                short8 a = *(const short8*)&sH2[q * 2064 + h2px * 8];
                acc3[jm] = MFMA16(a, w, acc3[jm]);
            }
        }
    }
    if (l15 == 0) {
#pragma unroll
        for (int jm = 0; jm < 3; ++jm) {
            if (jm < nm) {
                int mt = wv + 4 * jm;
#pragma unroll
                for (int r = 0; r < 4; ++r) {
                    int pp = mt * 16 + q * 4 + r;
                    int oy = (pp * 683) >> 13, ox = pp - 12 * oy;
                    int gy = oy0 + oy, gx = ox0 + ox;
                    if (gy < H && gx < W) {
                        size_t o = (size_t)b * outW * outH + (size_t)(gy * s2 + ppy) * outW + (gx * s2 + ppx);
                        out[o] = acc3[jm][r] + b3;
                    }
                }
            }
        }
    }
}

// ---------------------------------------------------------------------------
// MSF input: up4(out_x2) + up2(out_x4) + out_x8 (bilinear, half-pixel, clamped)
// ---------------------------------------------------------------------------
__device__ __forceinline__ void ax_w(int i, float inv_s, int n, int& i0, int& i1, float& w1) {
    float c  = (i + 0.5f) * inv_s - 0.5f;
    float fl = floorf(c);
    w1 = c - fl;
    int ii = (int)fl;
    i0 = ii < 0 ? 0 : ii;
    i1 = (ii + 1 >= n) ? (n - 1) : (ii + 1);
}

__global__ __launch_bounds__(256) void msf_in_kernel(
    const float* __restrict__ f2, const float* __restrict__ f4,
    const float* __restrict__ f8, float* __restrict__ dst)
{
    int idx = blockIdx.x * 256 + threadIdx.x;   // 4*512*512
    int x = idx & 511;
    int y = (idx >> 9) & 511;
    int b = idx >> 18;

    int y0, y1, x0, x1;
    float wy, wx;

    ax_w(y, 0.25f, 128, y0, y1, wy);
    ax_w(x, 0.25f, 128, x0, x1, wx);
    const float* p2 = f2 + (size_t)b * 16384;
    float v4 = (1.f - wy) * ((1.f - wx) * p2[y0 * 128 + x0] + wx * p2[y0 * 128 + x1])
             +        wy  * ((1.f - wx) * p2[y1 * 128 + x0] + wx * p2[y1 * 128 + x1]);

    ax_w(y, 0.5f, 256, y0, y1, wy);
    ax_w(x, 0.5f, 256, x0, x1, wx);
    const float* p4 = f4 + (size_t)b * 65536;
    float v2 = (1.f - wy) * ((1.f - wx) * p4[y0 * 256 + x0] + wx * p4[y0 * 256 + x1])
             +        wy  * ((1.f - wx) * p4[y1 * 256 + x0] + wx * p4[y1 * 256 + x1]);

    dst[idx] = v4 + v2 + f8[idx];
}

// ---------------------------------------------------------------------------
extern "C" void kernel_launch(void* const* d_in, const int* in_sizes, int n_in,
                              void* d_out, int out_size, void* d_ws, size_t ws_size,
                              hipStream_t stream)
{
    (void)in_sizes; (void)n_in; (void)out_size; (void)ws_size;

    const float* image = (const float*)d_in[0];
    const float* W1    = (const float*)d_in[1];
    const float* B1    = (const float*)d_in[2];
    const float* W2    = (const float*)d_in[3];
    const float* B2    = (const float*)d_in[4];
    const float* W3    = (const float*)d_in[5];
    const float* B3    = (const float*)d_in[6];

    float* out = (float*)d_out;
    float* o2 = out;                 // (4,1,128,128)
    float* o4 = out + 65536;         // (4,1,256,256)
    float* o8 = out + 327680;        // (4,1,512,512)
    float* om = out + 1376256;       // msf (4,1,512,512)

    float*    fm  = (float*)d_ws;                              // 4 MB
    ushort_t* w1t = (ushort_t*)((char*)d_ws + 4194304);        // 79872 u16
    ushort_t* w2t = (ushort_t*)((char*)d_ws + 4354048);        // 665600 u16
    ushort_t* w3t = (ushort_t*)((char*)d_ws + 5685248);        // 10400 u16

    prep_weights<<<2600, 256, 0, stream>>>(W1, W2, W3, w1t, w2t, w3t);

    srcnn_mfma<<<dim3(6, 6, 16), 256, 0, stream>>>(
        image, 64, 64, w1t, w2t, w3t, B1, B2, B3, 0, o2, 2);
    srcnn_mfma<<<dim3(11, 11, 16), 256, 0, stream>>>(
        o2, 128, 128, w1t, w2t, w3t, B1, B2, B3, 4, o4, 2);
    srcnn_mfma<<<dim3(22, 22, 16), 256, 0, stream>>>(
        o4, 256, 256, w1t, w2t, w3t, B1, B2, B3, 8, o8, 2);
    msf_in_kernel<<<4096, 256, 0, stream>>>(o2, o4, o8, fm);
    srcnn_mfma<<<dim3(43, 43, 4), 256, 0, stream>>>(
        fm, 512, 512, w1t, w2t, w3t, B1, B2, B3, 12, om, 1);
}

// Round 12
// 1075.194 us; speedup vs baseline: 2.5048x; 1.1570x over previous
//
#include <hip/hip_runtime.h>

// DSDMSR_x8: 13-unit SRCNN cascade, fp32 I/O, bf16 MFMA compute.
// Per 12x12 output tile (256 thr / 4 waves, __launch_bounds__(256,2) -- never
// force occupancy; cut TRUE register demand so HW runs 3 waves/SIMD naturally.
// RULE (r11 lesson): every register-array index must be COMPILE-TIME -- any
// dynamic index puts the array in scratch (r11: 373 MB WRITE_SIZE from
// acc1h[im]/acc2[..][n] dynamic indexing).
//   phase 1: conv1 9x9 1->64: 2 ci-halves (runtime c ok: no reg-array idx) x
//            2 m-subsets (runtime ms ok), acc1h[4][2]=32 AGPR static; kc rolled
//   phase 2: conv2 5x5 64->32: n,c fully unrolled (4 static passes), scoped
//            Ba/Bb ping-pong (40 VGPR), acc2[4][2]=32 AGPR static
//   phase 3: conv3 5x5 32->1: tap-outer, acc3[3]=12 AGPR static
// LDS 52928 B (53248 alloc) x3 = 159.7 KB <= 160 KB -> 3 blocks/CU.
// Spill canary: WRITE_SIZE must be ~5 MB (r8-verified).

typedef unsigned short ushort_t;
typedef __attribute__((ext_vector_type(8))) short short8;   // 8 bf16
typedef __attribute__((ext_vector_type(4))) float f32x4;

__device__ __forceinline__ float us2f(ushort_t u) { return __uint_as_float(((unsigned int)u) << 16); }
__device__ __forceinline__ ushort_t f2us(float f) {
    unsigned int x = __float_as_uint(f);
    return (ushort_t)((x + 0x7fffu + ((x >> 16) & 1u)) >> 16);
}

#define MFMA16(a, b, c) __builtin_amdgcn_mfma_f32_16x16x32_bf16((a), (b), (c), 0, 0, 0)

// ---------------------------------------------------------------------------
// Weight prep (bf16, MFMA-fragment-friendly layouts):
//  w1t [u][kc3][cig4][ch64][8]          (k = kc*32+cig*8+e, zero for k>=81)
//  w2t [u][c2][dx5][dy5][cig4][co32][8] (ci = c*32+cig*8+e, tap = dy*5+dx)
//  w3t [u][tap25][ci32]
// ---------------------------------------------------------------------------
__global__ __launch_bounds__(256) void prep_weights(
    const float* __restrict__ W1, const float* __restrict__ W2, const float* __restrict__ W3,
    ushort_t* __restrict__ w1t, ushort_t* __restrict__ w2t, ushort_t* __restrict__ w3t)
{
    int i = blockIdx.x * 256 + threadIdx.x;
    if (i < 13 * 3 * 4 * 64 * 8) {           // 79872
        int e = i & 7, ch = (i >> 3) & 63, cig = (i >> 9) & 3;
        int r = i >> 11;                     // u*3 + kc
        int kc = r % 3, u = r / 3;
        int k = kc * 32 + cig * 8 + e;
        w1t[i] = (k < 81) ? f2us(W1[(u * 64 + ch) * 81 + k]) : (ushort_t)0;
    }
    if (i < 665600) {                        // 13*2*25*4*32*8
        int e = i & 7, co = (i >> 3) & 31, cig = (i >> 8) & 3;
        int r = i >> 10;                     // (u*2+c)*25 + s, s = dx*5+dy
        int s = r % 25, cc = r / 25;
        int dx = s / 5, dy = s - 5 * dx;
        int c = cc & 1, u = cc >> 1;
        int tap = dy * 5 + dx;
        int ci = c * 32 + cig * 8 + e;
        w2t[i] = f2us(W2[((u * 32 + co) * 64 + ci) * 25 + tap]);
    }
    if (i < 13 * 25 * 32) {                  // 10400
        int ci = i & 31, r = i >> 5;
        int tap = r % 25, u = r / 25;
        w3t[i] = f2us(W3[(u * 32 + ci) * 25 + tap]);
    }
}

// ---------------------------------------------------------------------------
__global__ __launch_bounds__(256, 2) void srcnn_mfma(
    const float* __restrict__ in, int H, int W,
    const ushort_t* __restrict__ w1t, const ushort_t* __restrict__ w2t,
    const ushort_t* __restrict__ w3t,
    const float* __restrict__ gB1, const float* __restrict__ gB2,
    const float* __restrict__ gB3,
    int unitBase, float* __restrict__ out, int s2)
{
    __shared__ __align__(16) char smem[52928];
    ushort_t* sH1  = (ushort_t*)smem;             // 8 planes x 3208 shorts = 51328 B
    ushort_t* sInU = (ushort_t*)(smem + 51328);   // 784 bf16 (conv1 only)
    ushort_t* sW3  = (ushort_t*)(smem + 51328);   // 800 u16 (after conv1)
    ushort_t* sH2  = (ushort_t*)smem;             // h2 4 x 2064 shorts (after conv2)

    const int t = threadIdx.x, lane = t & 63, wv = t >> 6;
    const int q = lane >> 4, l15 = lane & 15;
    const int z = blockIdx.z;
    const int k4 = (s2 == 2) ? (z >> 2) : 0;
    const int b  = (s2 == 2) ? (z & 3)  : z;
    const int unit = unitBase + k4;
    const int ppx = k4 & 1, ppy = k4 >> 1;
    const int ox0 = blockIdx.x * 12, oy0 = blockIdx.y * 12;
    const int outW = W * s2;
    const int outH = H * s2;
    const float* inb = in + (size_t)b * H * W;

    const char* w2u = (const char*)w2t + (size_t)unit * 102400;

    // conv2 B: 5-frag buffer loaded from L2 for group p, n-tile n:
    //   frag dy at p*10240 + dy*2048 + q*512 + (n*16+l15)*16
    auto loadB5 = [&](short8* buf, int p, int n) {
        const char* g = w2u + (size_t)p * 10240 + q * 512 + (n * 16 + l15) * 16;
#pragma unroll
        for (int dy = 0; dy < 5; ++dy)
            buf[dy] = *(const short8*)(g + dy * 2048);
    };

    // stage input 28x28 (origin -8, zero-padded) as bf16
    for (int idx = t; idx < 784; idx += 256) {
        int y = idx / 28, x = idx - 28 * y;
        int gy = oy0 - 8 + y, gx = ox0 - 8 + x;
        sInU[idx] = (gy >= 0 && gy < H && gx >= 0 && gx < W)
                    ? f2us(inb[(size_t)gy * W + gx]) : (ushort_t)0;
    }
    __syncthreads();

    const ushort_t* w1u = w1t + (size_t)unit * (3 * 4 * 64 * 8);

    // ---- phase 1: conv1, 2 ci-halves x 2 m-subsets; acc1h 32 AGPR static ----
#pragma unroll 1
    for (int c = 0; c < 2; ++c) {
        float bias0 = gB1[unit * 64 + c * 32 + l15];
        float bias1 = gB1[unit * 64 + c * 32 + 16 + l15];
#pragma unroll 1
        for (int ms = 0; ms < 2; ++ms) {
            const int mbase = ms * 16;               // m-tiles [mbase, ...] ∩ [0,25)
            const int nim = ms ? 3 : 4;
            f32x4 acc1h[4][2];
#pragma unroll
            for (int i = 0; i < 4; ++i) { acc1h[i][0] = (f32x4){0.f,0.f,0.f,0.f}; acc1h[i][1] = (f32x4){0.f,0.f,0.f,0.f}; }

#pragma unroll 1
            for (int kc = 0; kc < 3; ++kc) {
                short8 bh0 = *(const short8*)&w1u[((kc * 4 + q) * 64 + (c * 32 + l15)) * 8];
                short8 bh1 = *(const short8*)&w1u[((kc * 4 + q) * 64 + (c * 32 + 16 + l15)) * 8];
                int toff8[8];
#pragma unroll
                for (int j = 0; j < 8; ++j) {
                    int k = kc * 32 + q * 8 + j;
                    if (k < 81) { int ty = (k * 57) >> 9; toff8[j] = ty * 28 + (k - 9 * ty); }
                    else toff8[j] = -1;
                }
#pragma unroll
                for (int im = 0; im < 4; ++im) {
                    if (im < nim) {
                        int m = mbase + wv + im * 4;
                        if (m < 25) {
                            int px = m * 16 + l15;        // 0..399 (20x20 h1 grid)
                            int py1 = (px * 205) >> 12;
                            int base = py1 * 28 + (px - 20 * py1);
                            union { short8 v; ushort_t u[8]; } a;
#pragma unroll
                            for (int j = 0; j < 8; ++j) {
                                int o = toff8[j];
                                a.u[j] = (o >= 0) ? sInU[base + o] : (ushort_t)0;
                            }
                            acc1h[im][0] = MFMA16(a.v, bh0, acc1h[im][0]);
                            acc1h[im][1] = MFMA16(a.v, bh1, acc1h[im][1]);
                        }
                    }
                }
            }

            // writeback this (c, ms): sH1 [cig8][px400][8], plane stride 3208
#pragma unroll
            for (int im = 0; im < 4; ++im) {
                if (im < nim) {
                    int m = mbase + wv + im * 4;
                    if (m < 25) {
#pragma unroll
                        for (int nn = 0; nn < 2; ++nn) {
                            float bias = nn ? bias1 : bias0;
                            int cig = c * 4 + ((nn * 16 + l15) >> 3);
                            int e   = l15 & 7;
#pragma unroll
                            for (int r = 0; r < 4; ++r) {
                                int px = m * 16 + q * 4 + r;
                                int py1 = (px * 205) >> 12;
                                int px1 = px - 20 * py1;
                                int gy = oy0 - 4 + py1, gx = ox0 - 4 + px1;
                                float v = fmaxf(acc1h[im][nn][r] + bias, 0.f);
                                if (!(gy >= 0 && gy < H && gx >= 0 && gx < W)) v = 0.f;
                                sH1[cig * 3208 + px * 8 + e] = f2us(v);
                            }
                        }
                    }
                }
            }
        }
    }
    __syncthreads();   // all h1 written; all sInU reads done

    // stage w3 into sInU region (dead); visible to conv3 via the post-h2 barrier
    {
        const ushort_t* w3u = w3t + unit * 800;
        for (int i = t; i < 800; i += 256) sW3[i] = w3u[i];
    }

    // ---- phase 2: conv2; acc2 32 AGPR + scoped Ba/Bb 40 VGPR, ALL static ----
    f32x4 acc2[4][2];
#pragma unroll
    for (int i = 0; i < 4; ++i) { acc2[i][0] = (f32x4){0.f,0.f,0.f,0.f}; acc2[i][1] = (f32x4){0.f,0.f,0.f,0.f}; }

#pragma unroll
    for (int n = 0; n < 2; ++n) {
#pragma unroll
        for (int c = 0; c < 2; ++c) {
            short8 Ba[5], Bb[5];
            loadB5(Ba, c * 5, n);
            const ushort_t* base = &sH1[(c * 4 + q) * 3208];
#pragma unroll
            for (int dx = 0; dx < 5; ++dx) {
                const short8* cur = (dx & 1) ? Bb : Ba;   // compile-time
                short8*       nxt = (dx & 1) ? Ba : Bb;
                if (dx < 4) loadB5(nxt, c * 5 + dx + 1, n);
#pragma unroll
                for (int rel = 0; rel < 8; ++rel) {
                    int row = wv * 4 + rel;
                    short8 a = *(const short8*)&base[(row * 20 + l15 + dx) * 8];
                    const int dylo = rel - 3 < 0 ? 0 : rel - 3;
                    const int dyhi = rel < 4 ? rel : 4;
#pragma unroll
                    for (int dy = 0; dy < 5; ++dy) {
                        if (dy >= dylo && dy <= dyhi) {
                            int im = rel - dy;
                            acc2[im][n] = MFMA16(a, cur[dy], acc2[im][n]);
                        }
                    }
                }
            }
        }
    }
    __syncthreads();   // all sH1 reads done before h2 overwrites it

    // ---- h2 writeback [cog4][px256][8], stride 2064, into sH1 region ----
    {
        float bias0 = gB2[unit * 32 + l15];
        float bias1 = gB2[unit * 32 + 16 + l15];
#pragma unroll
        for (int im = 0; im < 4; ++im) {
            int hy = wv * 4 + im;
#pragma unroll
            for (int n = 0; n < 2; ++n) {
                int co = n * 16 + l15;
                float bias = n ? bias1 : bias0;
                int cog = co >> 3, e = co & 7;
#pragma unroll
                for (int r = 0; r < 4; ++r) {
                    int hx = q * 4 + r;
                    int gy = oy0 - 2 + hy, gx = ox0 - 2 + hx;
                    float v = fmaxf(acc2[im][n][r] + bias, 0.f);
                    if (!(gy >= 0 && gy < H && gx >= 0 && gx < W)) v = 0.f;
                    sH2[cog * 2064 + (hy * 16 + hx) * 8 + e] = f2us(v);
                }
            }
        }
    }
    __syncthreads();

    // ---- phase 3: conv3, tap-outer, w-frag hoisted; acc3 12 AGPR static ----
    float b3 = gB3[unit];
    const int nm = (wv == 0) ? 3 : 2;
    int oyj[3], oxj[3];
#pragma unroll
    for (int jm = 0; jm < 3; ++jm) {
        int p = (wv + 4 * jm) * 16 + l15;            // 0..143 valid range
        oyj[jm] = (p * 683) >> 13;
        oxj[jm] = p - 12 * oyj[jm];
    }
    f32x4 acc3[3];
#pragma unroll
    for (int jm = 0; jm < 3; ++jm) acc3[jm] = (f32x4){0.f, 0.f, 0.f, 0.f};

#pragma unroll 1
    for (int tap = 0; tap < 25; ++tap) {
        int dy = (tap * 13) >> 6, dx = tap - 5 * dy;
        short8 w = *(const short8*)&sW3[tap * 32 + q * 8];
#pragma unroll
        for (int jm = 0; jm < 3; ++jm) {
            if (jm < nm) {
                int h2px = (oyj[jm] + dy) * 16 + oxj[jm] + dx;
                short8 a = *(const short8*)&sH2[q * 2064 + h2px * 8];
                acc3[jm] = MFMA16(a, w, acc3[jm]);
            }
        }
    }
    if (l15 == 0) {
#pragma unroll
        for (int jm = 0; jm < 3; ++jm) {
            if (jm < nm) {
                int mt = wv + 4 * jm;
#pragma unroll
                for (int r = 0; r < 4; ++r) {
                    int pp = mt * 16 + q * 4 + r;
                    int oy = (pp * 683) >> 13, ox = pp - 12 * oy;
                    int gy = oy0 + oy, gx = ox0 + ox;
                    if (gy < H && gx < W) {
                        size_t o = (size_t)b * outW * outH + (size_t)(gy * s2 + ppy) * outW + (gx * s2 + ppx);
                        out[o] = acc3[jm][r] + b3;
                    }
                }
            }
        }
    }
}

// ---------------------------------------------------------------------------
// MSF input: up4(out_x2) + up2(out_x4) + out_x8 (bilinear, half-pixel, clamped)
// ---------------------------------------------------------------------------
__device__ __forceinline__ void ax_w(int i, float inv_s, int n, int& i0, int& i1, float& w1) {
    float c  = (i + 0.5f) * inv_s - 0.5f;
    float fl = floorf(c);
    w1 = c - fl;
    int ii = (int)fl;
    i0 = ii < 0 ? 0 : ii;
    i1 = (ii + 1 >= n) ? (n - 1) : (ii + 1);
}

__global__ __launch_bounds__(256) void msf_in_kernel(
    const float* __restrict__ f2, const float* __restrict__ f4,
    const float* __restrict__ f8, float* __restrict__ dst)
{
    int idx = blockIdx.x * 256 + threadIdx.x;   // 4*512*512
    int x = idx & 511;
    int y = (idx >> 9) & 511;
    int b = idx >> 18;

    int y0, y1, x0, x1;
    float wy, wx;

    ax_w(y, 0.25f, 128, y0, y1, wy);
    ax_w(x, 0.25f, 128, x0, x1, wx);
    const float* p2 = f2 + (size_t)b * 16384;
    float v4 = (1.f - wy) * ((1.f - wx) * p2[y0 * 128 + x0] + wx * p2[y0 * 128 + x1])
             +        wy  * ((1.f - wx) * p2[y1 * 128 + x0] + wx * p2[y1 * 128 + x1]);

    ax_w(y, 0.5f, 256, y0, y1, wy);
    ax_w(x, 0.5f, 256, x0, x1, wx);
    const float* p4 = f4 + (size_t)b * 65536;
    float v2 = (1.f - wy) * ((1.f - wx) * p4[y0 * 256 + x0] + wx * p4[y0 * 256 + x1])
             +        wy  * ((1.f - wx) * p4[y1 * 256 + x0] + wx * p4[y1 * 256 + x1]);

    dst[idx] = v4 + v2 + f8[idx];
}

// ---------------------------------------------------------------------------
extern "C" void kernel_launch(void* const* d_in, const int* in_sizes, int n_in,
                              void* d_out, int out_size, void* d_ws, size_t ws_size,
                              hipStream_t stream)
{
    (void)in_sizes; (void)n_in; (void)out_size; (void)ws_size;

    const float* image = (const float*)d_in[0];
    const float* W1    = (const float*)d_in[1];
    const float* B1    = (const float*)d_in[2];
    const float* W2    = (const float*)d_in[3];
    const float* B2    = (const float*)d_in[4];
    const float* W3    = (const float*)d_in[5];
    const float* B3    = (const float*)d_in[6];

    float* out = (float*)d_out;
    float* o2 = out;                 // (4,1,128,128)
    float* o4 = out + 65536;         // (4,1,256,256)
    float* o8 = out + 327680;        // (4,1,512,512)
    float* om = out + 1376256;       // msf (4,1,512,512)

    float*    fm  = (float*)d_ws;                              // 4 MB
    ushort_t* w1t = (ushort_t*)((char*)d_ws + 4194304);        // 79872 u16
    ushort_t* w2t = (ushort_t*)((char*)d_ws + 4354048);        // 665600 u16
    ushort_t* w3t = (ushort_t*)((char*)d_ws + 5685248);        // 10400 u16

    prep_weights<<<2600, 256, 0, stream>>>(W1, W2, W3, w1t, w2t, w3t);

    srcnn_mfma<<<dim3(6, 6, 16), 256, 0, stream>>>(
        image, 64, 64, w1t, w2t, w3t, B1, B2, B3, 0, o2, 2);
    srcnn_mfma<<<dim3(11, 11, 16), 256, 0, stream>>>(
        o2, 128, 128, w1t, w2t, w3t, B1, B2, B3, 4, o4, 2);
    srcnn_mfma<<<dim3(22, 22, 16), 256, 0, stream>>>(
        o4, 256, 256, w1t, w2t, w3t, B1, B2, B3, 8, o8, 2);
    msf_in_kernel<<<4096, 256, 0, stream>>>(o2, o4, o8, fm);
    srcnn_mfma<<<dim3(43, 43, 4), 256, 0, stream>>>(
        fm, 512, 512, w1t, w2t, w3t, B1, B2, B3, 12, om, 1);
}

// Round 13
// 993.311 us; speedup vs baseline: 2.7113x; 1.0824x over previous
//
#include <hip/hip_runtime.h>

// DSDMSR_x8: 13-unit SRCNN cascade, fp32 I/O, bf16 MFMA compute.
// Per 12x12 output tile (256 thr / 4 waves, __launch_bounds__(256,2) -- never
// force occupancy; keep TRUE register demand <~170 so HW runs 3 waves/SIMD).
// RULES learned: (r8) disjoint accumulator lifetimes; (r11) every register-
// array index must be compile-time; (r11/r12) never cap occupancy below demand.
//   phase 1: conv1 9x9 1->64: FUSED ci (acc1h[4][4]=64 AGPR static) x
//            2 m-subsets; one A-build feeds 4 MFMAs (halves scalar LDS reads)
//   phase 2: conv2 5x5 64->32: n,c fully unrolled (4 static passes), scoped
//            Ba/Bb ping-pong (40 VGPR), acc2[4][2]=32 AGPR static
//   phase 3: conv3 5x5 32->1: tap-outer, acc3[3]=12 AGPR static
// Writeback OOB masks hoisted per-pixel (out of channel loops).
// LDS 52928 B (53248 alloc) x3 = 159.7 KB <= 160 KB -> 3 blocks/CU.
// Spill canary: WRITE_SIZE must be ~5 MB (r8/r12-verified).

typedef unsigned short ushort_t;
typedef __attribute__((ext_vector_type(8))) short short8;   // 8 bf16
typedef __attribute__((ext_vector_type(4))) float f32x4;

__device__ __forceinline__ float us2f(ushort_t u) { return __uint_as_float(((unsigned int)u) << 16); }
__device__ __forceinline__ ushort_t f2us(float f) {
    unsigned int x = __float_as_uint(f);
    return (ushort_t)((x + 0x7fffu + ((x >> 16) & 1u)) >> 16);
}

#define MFMA16(a, b, c) __builtin_amdgcn_mfma_f32_16x16x32_bf16((a), (b), (c), 0, 0, 0)

// ---------------------------------------------------------------------------
// Weight prep (bf16, MFMA-fragment-friendly layouts):
//  w1t [u][kc3][cig4][ch64][8]          (k = kc*32+cig*8+e, zero for k>=81)
//  w2t [u][c2][dx5][dy5][cig4][co32][8] (ci = c*32+cig*8+e, tap = dy*5+dx)
//  w3t [u][tap25][ci32]
// ---------------------------------------------------------------------------
__global__ __launch_bounds__(256) void prep_weights(
    const float* __restrict__ W1, const float* __restrict__ W2, const float* __restrict__ W3,
    ushort_t* __restrict__ w1t, ushort_t* __restrict__ w2t, ushort_t* __restrict__ w3t)
{
    int i = blockIdx.x * 256 + threadIdx.x;
    if (i < 13 * 3 * 4 * 64 * 8) {           // 79872
        int e = i & 7, ch = (i >> 3) & 63, cig = (i >> 9) & 3;
        int r = i >> 11;                     // u*3 + kc
        int kc = r % 3, u = r / 3;
        int k = kc * 32 + cig * 8 + e;
        w1t[i] = (k < 81) ? f2us(W1[(u * 64 + ch) * 81 + k]) : (ushort_t)0;
    }
    if (i < 665600) {                        // 13*2*25*4*32*8
        int e = i & 7, co = (i >> 3) & 31, cig = (i >> 8) & 3;
        int r = i >> 10;                     // (u*2+c)*25 + s, s = dx*5+dy
        int s = r % 25, cc = r / 25;
        int dx = s / 5, dy = s - 5 * dx;
        int c = cc & 1, u = cc >> 1;
        int tap = dy * 5 + dx;
        int ci = c * 32 + cig * 8 + e;
        w2t[i] = f2us(W2[((u * 32 + co) * 64 + ci) * 25 + tap]);
    }
    if (i < 13 * 25 * 32) {                  // 10400
        int ci = i & 31, r = i >> 5;
        int tap = r % 25, u = r / 25;
        w3t[i] = f2us(W3[(u * 32 + ci) * 25 + tap]);
    }
}

// ---------------------------------------------------------------------------
__global__ __launch_bounds__(256, 2) void srcnn_mfma(
    const float* __restrict__ in, int H, int W,
    const ushort_t* __restrict__ w1t, const ushort_t* __restrict__ w2t,
    const ushort_t* __restrict__ w3t,
    const float* __restrict__ gB1, const float* __restrict__ gB2,
    const float* __restrict__ gB3,
    int unitBase, float* __restrict__ out, int s2)
{
    __shared__ __align__(16) char smem[52928];
    ushort_t* sH1  = (ushort_t*)smem;             // 8 planes x 3208 shorts = 51328 B
    ushort_t* sInU = (ushort_t*)(smem + 51328);   // 784 bf16 (conv1 only)
    ushort_t* sW3  = (ushort_t*)(smem + 51328);   // 800 u16 (after conv1)
    ushort_t* sH2  = (ushort_t*)smem;             // h2 4 x 2064 shorts (after conv2)

    const int t = threadIdx.x, lane = t & 63, wv = t >> 6;
    const int q = lane >> 4, l15 = lane & 15;
    const int z = blockIdx.z;
    const int k4 = (s2 == 2) ? (z >> 2) : 0;
    const int b  = (s2 == 2) ? (z & 3)  : z;
    const int unit = unitBase + k4;
    const int ppx = k4 & 1, ppy = k4 >> 1;
    const int ox0 = blockIdx.x * 12, oy0 = blockIdx.y * 12;
    const int outW = W * s2;
    const int outH = H * s2;
    const float* inb = in + (size_t)b * H * W;

    const char* w2u = (const char*)w2t + (size_t)unit * 102400;

    // conv2 B: 5-frag buffer loaded from L2 for group p, n-tile n:
    //   frag dy at p*10240 + dy*2048 + q*512 + (n*16+l15)*16
    auto loadB5 = [&](short8* buf, int p, int n) {
        const char* g = w2u + (size_t)p * 10240 + q * 512 + (n * 16 + l15) * 16;
#pragma unroll
        for (int dy = 0; dy < 5; ++dy)
            buf[dy] = *(const short8*)(g + dy * 2048);
    };

    // stage input 28x28 (origin -8, zero-padded) as bf16
    for (int idx = t; idx < 784; idx += 256) {
        int y = idx / 28, x = idx - 28 * y;
        int gy = oy0 - 8 + y, gx = ox0 - 8 + x;
        sInU[idx] = (gy >= 0 && gy < H && gx >= 0 && gx < W)
                    ? f2us(inb[(size_t)gy * W + gx]) : (ushort_t)0;
    }
    __syncthreads();

    const ushort_t* w1u = w1t + (size_t)unit * (3 * 4 * 64 * 8);

    // ---- phase 1: conv1, fused ci (4 n-tiles), 2 m-subsets ----
    float biasN[4];
#pragma unroll
    for (int n = 0; n < 4; ++n) biasN[n] = gB1[unit * 64 + n * 16 + l15];

#pragma unroll 1
    for (int ms = 0; ms < 2; ++ms) {
        const int mbase = ms * 16;               // m-tiles [mbase, ...] ∩ [0,25)
        const int nim = ms ? 3 : 4;
        f32x4 acc1h[4][4];                       // [im][n] all-static
#pragma unroll
        for (int i = 0; i < 4; ++i)
#pragma unroll
            for (int n = 0; n < 4; ++n) acc1h[i][n] = (f32x4){0.f, 0.f, 0.f, 0.f};

#pragma unroll 1
        for (int kc = 0; kc < 3; ++kc) {
            short8 bh[4];
#pragma unroll
            for (int n = 0; n < 4; ++n)
                bh[n] = *(const short8*)&w1u[((kc * 4 + q) * 64 + n * 16 + l15) * 8];
            int toff8[8];
#pragma unroll
            for (int j = 0; j < 8; ++j) {
                int k = kc * 32 + q * 8 + j;
                if (k < 81) { int ty = (k * 57) >> 9; toff8[j] = ty * 28 + (k - 9 * ty); }
                else toff8[j] = -1;
            }
#pragma unroll
            for (int im = 0; im < 4; ++im) {
                if (im < nim) {
                    int m = mbase + wv + im * 4;
                    if (m < 25) {
                        int px = m * 16 + l15;        // 0..399 (20x20 h1 grid)
                        int py1 = (px * 205) >> 12;
                        int base = py1 * 28 + (px - 20 * py1);
                        union { short8 v; ushort_t u[8]; } a;
#pragma unroll
                        for (int j = 0; j < 8; ++j) {
                            int o = toff8[j];
                            a.u[j] = (o >= 0) ? sInU[base + o] : (ushort_t)0;
                        }
#pragma unroll
                        for (int n = 0; n < 4; ++n)
                            acc1h[im][n] = MFMA16(a.v, bh[n], acc1h[im][n]);
                    }
                }
            }
        }

        // writeback all 64 channels for this m-subset; mask hoisted per pixel
#pragma unroll
        for (int im = 0; im < 4; ++im) {
            if (im < nim) {
                int m = mbase + wv + im * 4;
                if (m < 25) {
#pragma unroll
                    for (int r = 0; r < 4; ++r) {
                        int px = m * 16 + q * 4 + r;
                        int py1 = (px * 205) >> 12;
                        int px1 = px - 20 * py1;
                        int gy = oy0 - 4 + py1, gx = ox0 - 4 + px1;
                        bool ok = (gy >= 0 && gy < H && gx >= 0 && gx < W);
                        int e = l15 & 7;
                        int ch = l15 >> 3;
#pragma unroll
                        for (int n = 0; n < 4; ++n) {
                            float v = fmaxf(acc1h[im][n][r] + biasN[n], 0.f);
                            if (!ok) v = 0.f;
                            sH1[(n * 2 + ch) * 3208 + px * 8 + e] = f2us(v);
                        }
                    }
                }
            }
        }
    }
    __syncthreads();   // all h1 written; all sInU reads done

    // stage w3 into sInU region (dead); visible to conv3 via the post-h2 barrier
    {
        const ushort_t* w3u = w3t + unit * 800;
        for (int i = t; i < 800; i += 256) sW3[i] = w3u[i];
    }

    // ---- phase 2: conv2; acc2 32 AGPR + scoped Ba/Bb 40 VGPR, ALL static ----
    f32x4 acc2[4][2];
#pragma unroll
    for (int i = 0; i < 4; ++i) { acc2[i][0] = (f32x4){0.f,0.f,0.f,0.f}; acc2[i][1] = (f32x4){0.f,0.f,0.f,0.f}; }

#pragma unroll
    for (int n = 0; n < 2; ++n) {
#pragma unroll
        for (int c = 0; c < 2; ++c) {
            short8 Ba[5], Bb[5];
            loadB5(Ba, c * 5, n);
            const ushort_t* base = &sH1[(c * 4 + q) * 3208];
#pragma unroll
            for (int dx = 0; dx < 5; ++dx) {
                const short8* cur = (dx & 1) ? Bb : Ba;   // compile-time
                short8*       nxt = (dx & 1) ? Ba : Bb;
                if (dx < 4) loadB5(nxt, c * 5 + dx + 1, n);
#pragma unroll
                for (int rel = 0; rel < 8; ++rel) {
                    int row = wv * 4 + rel;
                    short8 a = *(const short8*)&base[(row * 20 + l15 + dx) * 8];
                    const int dylo = rel - 3 < 0 ? 0 : rel - 3;
                    const int dyhi = rel < 4 ? rel : 4;
#pragma unroll
                    for (int dy = 0; dy < 5; ++dy) {
                        if (dy >= dylo && dy <= dyhi) {
                            int im = rel - dy;
                            acc2[im][n] = MFMA16(a, cur[dy], acc2[im][n]);
                        }
                    }
                }
            }
        }
    }
    __syncthreads();   // all sH1 reads done before h2 overwrites it

    // ---- h2 writeback [cog4][px256][8], stride 2064; mask hoisted per pixel ----
    {
        float bias0 = gB2[unit * 32 + l15];
        float bias1 = gB2[unit * 32 + 16 + l15];
#pragma unroll
        for (int im = 0; im < 4; ++im) {
            int hy = wv * 4 + im;
#pragma unroll
            for (int r = 0; r < 4; ++r) {
                int hx = q * 4 + r;
                int gy = oy0 - 2 + hy, gx = ox0 - 2 + hx;
                bool ok = (gy >= 0 && gy < H && gx >= 0 && gx < W);
                int e = l15 & 7;
                int ch = l15 >> 3;
#pragma unroll
                for (int n = 0; n < 2; ++n) {
                    float v = fmaxf(acc2[im][n][r] + (n ? bias1 : bias0), 0.f);
                    if (!ok) v = 0.f;
                    sH2[(n * 2 + ch) * 2064 + (hy * 16 + hx) * 8 + e] = f2us(v);
                }
            }
        }
    }
    __syncthreads();

    // ---- phase 3: conv3, tap-outer, w-frag hoisted; acc3 12 AGPR static ----
    float b3 = gB3[unit];
    const int nm = (wv == 0) ? 3 : 2;
    int oyj[3], oxj[3];
#pragma unroll
    for (int jm = 0; jm < 3; ++jm) {
        int p = (wv + 4 * jm) * 16 + l15;            // 0..143 valid range
        oyj[jm] = (p * 683) >> 13;
        oxj[jm] = p - 12 * oyj[jm];
    }
    f32x4 acc3[3];
#pragma unroll
    for (int jm = 0; jm < 3; ++jm) acc3[jm] = (f32x4){0.f, 0.f, 0.f, 0.f};

#pragma unroll 1
    for (int tap = 0; tap < 25; ++tap) {
        int dy = (tap * 13) >> 6, dx = tap - 5 * dy;
        short8 w = *(const short8*)&sW3[tap * 32 + q * 8];
#pragma unroll
        for (int jm = 0; jm < 3; ++jm) {
            if (jm < nm) {
                int h2px = (oyj[jm] + dy) * 16 + oxj[jm] + dx;
                short8 a = *(const short8*)&sH2[q * 2064 + h2px * 8];
                acc3[jm] = MFMA16(a, w, acc3[jm]);
            }
        }
    }
    if (l15 == 0) {
#pragma unroll
        for (int jm = 0; jm < 3; ++jm) {
            if (jm < nm) {
                int mt = wv + 4 * jm;
#pragma unroll
                for (int r = 0; r < 4; ++r) {
                    int pp = mt * 16 + q * 4 + r;
                    int oy = (pp * 683) >> 13, ox = pp - 12 * oy;
                    int gy = oy0 + oy, gx = ox0 + ox;
                    if (gy < H && gx < W) {
                        size_t o = (size_t)b * outW * outH + (size_t)(gy * s2 + ppy) * outW + (gx * s2 + ppx);
                        out[o] = acc3[jm][r] + b3;
                    }
                }
            }
        }
    }
}

// ---------------------------------------------------------------------------
// MSF input: up4(out_x2) + up2(out_x4) + out_x8 (bilinear, half-pixel, clamped)
// ---------------------------------------------------------------------------
__device__ __forceinline__ void ax_w(int i, float inv_s, int n, int& i0, int& i1, float& w1) {
    float c  = (i + 0.5f) * inv_s - 0.5f;
    float fl = floorf(c);
    w1 = c - fl;
    int ii = (int)fl;
    i0 = ii < 0 ? 0 : ii;
    i1 = (ii + 1 >= n) ? (n - 1) : (ii + 1);
}

__global__ __launch_bounds__(256) void msf_in_kernel(
    const float* __restrict__ f2, const float* __restrict__ f4,
    const float* __restrict__ f8, float* __restrict__ dst)
{
    int idx = blockIdx.x * 256 + threadIdx.x;   // 4*512*512
    int x = idx & 511;
    int y = (idx >> 9) & 511;
    int b = idx >> 18;

    int y0, y1, x0, x1;
    float wy, wx;

    ax_w(y, 0.25f, 128, y0, y1, wy);
    ax_w(x, 0.25f, 128, x0, x1, wx);
    const float* p2 = f2 + (size_t)b * 16384;
    float v4 = (1.f - wy) * ((1.f - wx) * p2[y0 * 128 + x0] + wx * p2[y0 * 128 + x1])
             +        wy  * ((1.f - wx) * p2[y1 * 128 + x0] + wx * p2[y1 * 128 + x1]);

    ax_w(y, 0.5f, 256, y0, y1, wy);
    ax_w(x, 0.5f, 256, x0, x1, wx);
    const float* p4 = f4 + (size_t)b * 65536;
    float v2 = (1.f - wy) * ((1.f - wx) * p4[y0 * 256 + x0] + wx * p4[y0 * 256 + x1])
             +        wy  * ((1.f - wx) * p4[y1 * 256 + x0] + wx * p4[y1 * 256 + x1]);

    dst[idx] = v4 + v2 + f8[idx];
}

// ---------------------------------------------------------------------------
extern "C" void kernel_launch(void* const* d_in, const int* in_sizes, int n_in,
                              void* d_out, int out_size, void* d_ws, size_t ws_size,
                              hipStream_t stream)
{
    (void)in_sizes; (void)n_in; (void)out_size; (void)ws_size;

    const float* image = (const float*)d_in[0];
    const float* W1    = (const float*)d_in[1];
    const float* B1    = (const float*)d_in[2];
    const float* W2    = (const float*)d_in[3];
    const float* B2    = (const float*)d_in[4];
    const float* W3    = (const float*)d_in[5];
    const float* B3    = (const float*)d_in[6];

    float* out = (float*)d_out;
    float* o2 = out;                 // (4,1,128,128)
    float* o4 = out + 65536;         // (4,1,256,256)
    float* o8 = out + 327680;        // (4,1,512,512)
    float* om = out + 1376256;       // msf (4,1,512,512)

    float*    fm  = (float*)d_ws;                              // 4 MB
    ushort_t* w1t = (ushort_t*)((char*)d_ws + 4194304);        // 79872 u16
    ushort_t* w2t = (ushort_t*)((char*)d_ws + 4354048);        // 665600 u16
    ushort_t* w3t = (ushort_t*)((char*)d_ws + 5685248);        // 10400 u16

    prep_weights<<<2600, 256, 0, stream>>>(W1, W2, W3, w1t, w2t, w3t);

    srcnn_mfma<<<dim3(6, 6, 16), 256, 0, stream>>>(
        image, 64, 64, w1t, w2t, w3t, B1, B2, B3, 0, o2, 2);
    srcnn_mfma<<<dim3(11, 11, 16), 256, 0, stream>>>(
        o2, 128, 128, w1t, w2t, w3t, B1, B2, B3, 4, o4, 2);
    srcnn_mfma<<<dim3(22, 22, 16), 256, 0, stream>>>(
        o4, 256, 256, w1t, w2t, w3t, B1, B2, B3, 8, o8, 2);
    msf_in_kernel<<<4096, 256, 0, stream>>>(o2, o4, o8, fm);
    srcnn_mfma<<<dim3(43, 43, 4), 256, 0, stream>>>(
        fm, 512, 512, w1t, w2t, w3t, B1, B2, B3, 12, om, 1);
}